// Round 1
// baseline (5440.819 us; speedup 1.0000x reference)
//
#include <hip/hip_runtime.h>

#define NN 10000
#define NE 160000

constexpr float INV_AVG = 1.0f / 16.0f;
constexpr float INV_SQRT3F = 0.5773502691896258f;

// ---------------------------------------------------------------------------
// Kernel A: per-node precompute.
//   hbuf[n][512]  : [0:128)=h0[k], [128+m*128+k)=h1[n,k,m]
//   out[n][512]   : [0:128)=sc0[n,k], 128+k*3+m = sc1[n,k,m]
// 16 nodes/block, 256 threads. thread: kq=t&31 (4 k), g=t>>5: sg=g&3 slice,
// nb=(g>>2)*8 node sub-tile. Slices: 0 -> x0/W*0 ; 1..3 -> x1[:,:,m]/W*1.
// ---------------------------------------------------------------------------
__global__ __launch_bounds__(256) void node_kernel(
    const float* __restrict__ node_attrs,
    const float* __restrict__ node_feats,
    const float* __restrict__ W_up0,
    const float* __restrict__ W_up1,
    const float* __restrict__ W_sk0,
    const float* __restrict__ W_sk1,
    float* __restrict__ hbuf,
    float* __restrict__ out)
{
    __shared__ float xs[16][512];
    __shared__ float at[16][10];
    const int t = threadIdx.x;
    const int n0 = blockIdx.x * 16;

    {
        const float4* src = (const float4*)(node_feats + (size_t)n0 * 512);
        float4* dst = (float4*)&xs[0][0];
        #pragma unroll
        for (int i = 0; i < 8; ++i) dst[t + i * 256] = src[t + i * 256];
    }
    if (t < 160) ((float*)at)[t] = node_attrs[n0 * 10 + t];
    __syncthreads();

    const int kq = t & 31;
    const int g  = t >> 5;
    const int sg = g & 3;
    const int nb = (g >> 2) * 8;

    // ---- phase H: h = x_slice @ Wup ----
    {
        const float* __restrict__ Wup = (sg == 0) ? W_up0 : W_up1;
        float acc[8][4];
        #pragma unroll
        for (int n = 0; n < 8; ++n)
            #pragma unroll
            for (int j = 0; j < 4; ++j) acc[n][j] = 0.f;

        for (int u = 0; u < 128; ++u) {
            const float4 w = *(const float4*)(Wup + u * 128 + kq * 4);
            const int xi = (sg == 0) ? u : (128 + u * 3 + (sg - 1));
            #pragma unroll
            for (int n = 0; n < 8; ++n) {
                const float xv = xs[nb + n][xi];
                acc[n][0] += xv * w.x;
                acc[n][1] += xv * w.y;
                acc[n][2] += xv * w.z;
                acc[n][3] += xv * w.w;
            }
        }
        #pragma unroll
        for (int n = 0; n < 8; ++n) {
            float4 v = make_float4(acc[n][0], acc[n][1], acc[n][2], acc[n][3]);
            *(float4*)(hbuf + (size_t)(n0 + nb + n) * 512 + sg * 128 + kq * 4) = v;
        }
    }

    // ---- phase SC: sc = sum_a attrs[:,a] * (x_slice @ Wsk[:,a,:]) ----
    {
        const float* __restrict__ Wsk = (sg == 0) ? W_sk0 : W_sk1;
        float acc[8][4];
        #pragma unroll
        for (int n = 0; n < 8; ++n)
            #pragma unroll
            for (int j = 0; j < 4; ++j) acc[n][j] = 0.f;

        for (int a = 0; a < 10; ++a) {
            float part[8][4];
            #pragma unroll
            for (int n = 0; n < 8; ++n)
                #pragma unroll
                for (int j = 0; j < 4; ++j) part[n][j] = 0.f;

            for (int u = 0; u < 128; ++u) {
                const float4 w = *(const float4*)(Wsk + (u * 10 + a) * 128 + kq * 4);
                const int xi = (sg == 0) ? u : (128 + u * 3 + (sg - 1));
                #pragma unroll
                for (int n = 0; n < 8; ++n) {
                    const float xv = xs[nb + n][xi];
                    part[n][0] += xv * w.x;
                    part[n][1] += xv * w.y;
                    part[n][2] += xv * w.z;
                    part[n][3] += xv * w.w;
                }
            }
            #pragma unroll
            for (int n = 0; n < 8; ++n) {
                const float av = at[nb + n][a];
                acc[n][0] += av * part[n][0];
                acc[n][1] += av * part[n][1];
                acc[n][2] += av * part[n][2];
                acc[n][3] += av * part[n][3];
            }
        }
        #pragma unroll
        for (int n = 0; n < 8; ++n) {
            float* orow = out + (size_t)(n0 + nb + n) * 512;
            if (sg == 0) {
                *(float4*)(orow + kq * 4) =
                    make_float4(acc[n][0], acc[n][1], acc[n][2], acc[n][3]);
            } else {
                const int m = sg - 1;
                #pragma unroll
                for (int j = 0; j < 4; ++j)
                    orow[128 + (kq * 4 + j) * 3 + m] = acc[n][j];
            }
        }
    }
}

// ---------------------------------------------------------------------------
// Kernel B: per-edge. Computes tpw quarter-by-quarter in registers (never
// materialized), forms message components, atomicAdd into msgbuf[n][1024]:
//   [0:128)=m0a, [128:256)=m0b, 256+m*256+k = m1a, 256+m*256+128+k = m1b
// 128 edges/block, 256 threads: kq=t&15 (8 k), eg=t>>4 (8 edges).
// ---------------------------------------------------------------------------
__global__ __launch_bounds__(256) void edge_kernel(
    const float* __restrict__ node_attrs,
    const float* __restrict__ edge_attrs,
    const float* __restrict__ edge_feats,
    const int*  __restrict__ edge_index,
    const float* __restrict__ W_tpw,
    const float* __restrict__ hbuf,
    float* __restrict__ msgbuf)
{
    __shared__ float z[80][128];      // z[a*8+j][e] = attrs[s_e][a]*ef[e][j]
    __shared__ float Y0s[128];
    __shared__ float Y1s[128][3];
    __shared__ int   ss[128];
    __shared__ int   rs[128];
    __shared__ float efs[128][8];
    __shared__ float ats[128][10];

    const int t = threadIdx.x;
    const int e0 = blockIdx.x * 128;

    if (t < 128) {
        const int e = e0 + t;
        ss[t] = edge_index[e];
        rs[t] = edge_index[NE + e];
        const float4 ea = *(const float4*)(edge_attrs + (size_t)e * 4);
        Y0s[t] = ea.x; Y1s[t][0] = ea.y; Y1s[t][1] = ea.z; Y1s[t][2] = ea.w;
    }
    {
        const float4* src = (const float4*)(edge_feats + (size_t)e0 * 8);
        ((float4*)&efs[0][0])[t] = src[t];
    }
    __syncthreads();

    for (int i = t; i < 1280; i += 256) {
        const int e = i / 10, a = i - e * 10;
        ats[e][a] = node_attrs[ss[e] * 10 + a];
    }
    __syncthreads();

    for (int i = t; i < 80 * 128; i += 256) {
        const int ae = i >> 7, e = i & 127;
        z[ae][e] = ats[e][ae >> 3] * efs[e][ae & 7];
    }
    __syncthreads();

    const int kq = t & 15;   // k = kq*8 .. +7
    const int eg = t >> 4;   // edges eg*8 .. +7

    for (int q = 0; q < 4; ++q) {
        float acc[8][8];
        #pragma unroll
        for (int ei = 0; ei < 8; ++ei)
            #pragma unroll
            for (int j = 0; j < 8; ++j) acc[ei][j] = 0.f;

        const float* __restrict__ Wq = W_tpw + q * 128 + kq * 8;
        for (int ae = 0; ae < 80; ++ae) {
            const float4 wa = *(const float4*)(Wq + ae * 512);
            const float4 wb = *(const float4*)(Wq + ae * 512 + 4);
            const float4 za = *(const float4*)&z[ae][eg * 8];
            const float4 zb = *(const float4*)&z[ae][eg * 8 + 4];
            const float zv[8] = {za.x, za.y, za.z, za.w, zb.x, zb.y, zb.z, zb.w};
            #pragma unroll
            for (int ei = 0; ei < 8; ++ei) {
                acc[ei][0] += zv[ei] * wa.x;
                acc[ei][1] += zv[ei] * wa.y;
                acc[ei][2] += zv[ei] * wa.z;
                acc[ei][3] += zv[ei] * wa.w;
                acc[ei][4] += zv[ei] * wb.x;
                acc[ei][5] += zv[ei] * wb.y;
                acc[ei][6] += zv[ei] * wb.z;
                acc[ei][7] += zv[ei] * wb.w;
            }
        }

        for (int ei = 0; ei < 8; ++ei) {
            const int e = eg * 8 + ei;
            const int s = ss[e], r = rs[e];
            const float* hrow = hbuf + (size_t)s * 512;
            float* mrow = msgbuf + (size_t)r * 1024;
            const float y0 = Y0s[e];

            if (q == 0) {
                const float4 ha = *(const float4*)(hrow + kq * 8);
                const float4 hb = *(const float4*)(hrow + kq * 8 + 4);
                const float hv[8] = {ha.x, ha.y, ha.z, ha.w, hb.x, hb.y, hb.z, hb.w};
                #pragma unroll
                for (int j = 0; j < 8; ++j)
                    atomicAdd(mrow + kq * 8 + j, acc[ei][j] * hv[j] * y0);
            } else if (q == 1) {
                const float4 ha = *(const float4*)(hrow + kq * 8);
                const float4 hb = *(const float4*)(hrow + kq * 8 + 4);
                const float hv[8] = {ha.x, ha.y, ha.z, ha.w, hb.x, hb.y, hb.z, hb.w};
                const float y10 = Y1s[e][0], y11 = Y1s[e][1], y12 = Y1s[e][2];
                #pragma unroll
                for (int j = 0; j < 8; ++j) {
                    const float tm = acc[ei][j] * hv[j];
                    atomicAdd(mrow + 256 + 0 * 256 + kq * 8 + j, tm * y10);
                    atomicAdd(mrow + 256 + 1 * 256 + kq * 8 + j, tm * y11);
                    atomicAdd(mrow + 256 + 2 * 256 + kq * 8 + j, tm * y12);
                }
            } else if (q == 2) {
                #pragma unroll
                for (int m = 0; m < 3; ++m) {
                    const float4 ha = *(const float4*)(hrow + 128 + m * 128 + kq * 8);
                    const float4 hb = *(const float4*)(hrow + 128 + m * 128 + kq * 8 + 4);
                    const float hv[8] = {ha.x, ha.y, ha.z, ha.w, hb.x, hb.y, hb.z, hb.w};
                    #pragma unroll
                    for (int j = 0; j < 8; ++j)
                        atomicAdd(mrow + 256 + m * 256 + 128 + kq * 8 + j,
                                  acc[ei][j] * y0 * hv[j]);
                }
            } else {
                float d[8];
                #pragma unroll
                for (int j = 0; j < 8; ++j) d[j] = 0.f;
                #pragma unroll
                for (int m = 0; m < 3; ++m) {
                    const float y1m = Y1s[e][m];
                    const float4 ha = *(const float4*)(hrow + 128 + m * 128 + kq * 8);
                    const float4 hb = *(const float4*)(hrow + 128 + m * 128 + kq * 8 + 4);
                    const float hv[8] = {ha.x, ha.y, ha.z, ha.w, hb.x, hb.y, hb.z, hb.w};
                    #pragma unroll
                    for (int j = 0; j < 8; ++j) d[j] += hv[j] * y1m;
                }
                #pragma unroll
                for (int j = 0; j < 8; ++j)
                    atomicAdd(mrow + 128 + kq * 8 + j,
                              acc[ei][j] * INV_SQRT3F * d[j]);
            }
        }
    }
}

// ---------------------------------------------------------------------------
// Kernel C: out += (msg @ W_lin) / 16.  16 nodes/block, 4 slices.
// ---------------------------------------------------------------------------
__global__ __launch_bounds__(256) void out_kernel(
    const float* __restrict__ msgbuf,
    const float* __restrict__ W_lin0,
    const float* __restrict__ W_lin1,
    float* __restrict__ out)
{
    __shared__ float ms[16][256];
    const int t = threadIdx.x;
    const int n0 = blockIdx.x * 16;
    const int kq = t & 31;  // 4 k
    const int g  = t >> 5;  // 2 nodes

    for (int s = 0; s < 4; ++s) {
        __syncthreads();
        const int coff = (s == 0) ? 0 : (256 + (s - 1) * 256);
        for (int i = t; i < 1024; i += 256) {
            const int n = i >> 6, c4 = i & 63;
            ((float4*)&ms[n][0])[c4] =
                *(const float4*)(msgbuf + (size_t)(n0 + n) * 1024 + coff + c4 * 4);
        }
        __syncthreads();

        const float* __restrict__ Wl = (s == 0) ? W_lin0 : W_lin1;
        float acc[2][4];
        #pragma unroll
        for (int n = 0; n < 2; ++n)
            #pragma unroll
            for (int j = 0; j < 4; ++j) acc[n][j] = 0.f;

        for (int U = 0; U < 256; ++U) {
            const float4 w = *(const float4*)(Wl + U * 128 + kq * 4);
            #pragma unroll
            for (int n = 0; n < 2; ++n) {
                const float mv = ms[g * 2 + n][U];
                acc[n][0] += mv * w.x;
                acc[n][1] += mv * w.y;
                acc[n][2] += mv * w.z;
                acc[n][3] += mv * w.w;
            }
        }
        #pragma unroll
        for (int n = 0; n < 2; ++n) {
            float* orow = out + (size_t)(n0 + g * 2 + n) * 512;
            if (s == 0) {
                float4 o = *(float4*)(orow + kq * 4);
                o.x += acc[n][0] * INV_AVG;
                o.y += acc[n][1] * INV_AVG;
                o.z += acc[n][2] * INV_AVG;
                o.w += acc[n][3] * INV_AVG;
                *(float4*)(orow + kq * 4) = o;
            } else {
                const int m = s - 1;
                #pragma unroll
                for (int j = 0; j < 4; ++j)
                    orow[128 + (kq * 4 + j) * 3 + m] += acc[n][j] * INV_AVG;
            }
        }
    }
}

extern "C" void kernel_launch(void* const* d_in, const int* in_sizes, int n_in,
                              void* d_out, int out_size, void* d_ws, size_t ws_size,
                              hipStream_t stream) {
    const float* node_attrs = (const float*)d_in[0];
    const float* node_feats = (const float*)d_in[1];
    const float* edge_attrs = (const float*)d_in[2];
    const float* edge_feats = (const float*)d_in[3];
    const int*   edge_index = (const int*)d_in[4];
    const float* W_up0  = (const float*)d_in[5];
    const float* W_up1  = (const float*)d_in[6];
    const float* W_tpw  = (const float*)d_in[7];
    const float* W_lin0 = (const float*)d_in[8];
    const float* W_lin1 = (const float*)d_in[9];
    const float* W_sk0  = (const float*)d_in[10];
    const float* W_sk1  = (const float*)d_in[11];
    float* out = (float*)d_out;

    float* hbuf   = (float*)d_ws;                       // NN*512 f32 = 20.5 MB
    float* msgbuf = hbuf + (size_t)NN * 512;            // NN*1024 f32 = 41 MB

    hipMemsetAsync(msgbuf, 0, (size_t)NN * 1024 * sizeof(float), stream);

    node_kernel<<<NN / 16, 256, 0, stream>>>(node_attrs, node_feats,
                                             W_up0, W_up1, W_sk0, W_sk1,
                                             hbuf, out);
    edge_kernel<<<NE / 128, 256, 0, stream>>>(node_attrs, edge_attrs, edge_feats,
                                              edge_index, W_tpw, hbuf, msgbuf);
    out_kernel<<<NN / 16, 256, 0, stream>>>(msgbuf, W_lin0, W_lin1, out);
}

// Round 2
// 1332.496 us; speedup vs baseline: 4.0832x; 4.0832x over previous
//
#include <hip/hip_runtime.h>

#define NN 10000
#define NE 160000

constexpr float INV_AVG = 1.0f / 16.0f;
constexpr float INV_SQRT3F = 0.5773502691896258f;

// ---------------------------------------------------------------------------
// Kernel A: per-node precompute (unchanged from R1).
//   hbuf[n][512]  : [0:128)=h0[k], 128+m*128+k = h1[n,k,m]
//   out[n][512]   : [0:128)=sc0[n,k], 128+k*3+m = sc1[n,k,m]
// ---------------------------------------------------------------------------
__global__ __launch_bounds__(256) void node_kernel(
    const float* __restrict__ node_attrs,
    const float* __restrict__ node_feats,
    const float* __restrict__ W_up0,
    const float* __restrict__ W_up1,
    const float* __restrict__ W_sk0,
    const float* __restrict__ W_sk1,
    float* __restrict__ hbuf,
    float* __restrict__ out)
{
    __shared__ float xs[16][512];
    __shared__ float at[16][10];
    const int t = threadIdx.x;
    const int n0 = blockIdx.x * 16;

    {
        const float4* src = (const float4*)(node_feats + (size_t)n0 * 512);
        float4* dst = (float4*)&xs[0][0];
        #pragma unroll
        for (int i = 0; i < 8; ++i) dst[t + i * 256] = src[t + i * 256];
    }
    if (t < 160) ((float*)at)[t] = node_attrs[n0 * 10 + t];
    __syncthreads();

    const int kq = t & 31;
    const int g  = t >> 5;
    const int sg = g & 3;
    const int nb = (g >> 2) * 8;

    // ---- phase H ----
    {
        const float* __restrict__ Wup = (sg == 0) ? W_up0 : W_up1;
        float acc[8][4];
        #pragma unroll
        for (int n = 0; n < 8; ++n)
            #pragma unroll
            for (int j = 0; j < 4; ++j) acc[n][j] = 0.f;

        for (int u = 0; u < 128; ++u) {
            const float4 w = *(const float4*)(Wup + u * 128 + kq * 4);
            const int xi = (sg == 0) ? u : (128 + u * 3 + (sg - 1));
            #pragma unroll
            for (int n = 0; n < 8; ++n) {
                const float xv = xs[nb + n][xi];
                acc[n][0] += xv * w.x;
                acc[n][1] += xv * w.y;
                acc[n][2] += xv * w.z;
                acc[n][3] += xv * w.w;
            }
        }
        #pragma unroll
        for (int n = 0; n < 8; ++n) {
            float4 v = make_float4(acc[n][0], acc[n][1], acc[n][2], acc[n][3]);
            *(float4*)(hbuf + (size_t)(n0 + nb + n) * 512 + sg * 128 + kq * 4) = v;
        }
    }

    // ---- phase SC ----
    {
        const float* __restrict__ Wsk = (sg == 0) ? W_sk0 : W_sk1;
        float acc[8][4];
        #pragma unroll
        for (int n = 0; n < 8; ++n)
            #pragma unroll
            for (int j = 0; j < 4; ++j) acc[n][j] = 0.f;

        for (int a = 0; a < 10; ++a) {
            float part[8][4];
            #pragma unroll
            for (int n = 0; n < 8; ++n)
                #pragma unroll
                for (int j = 0; j < 4; ++j) part[n][j] = 0.f;

            for (int u = 0; u < 128; ++u) {
                const float4 w = *(const float4*)(Wsk + (u * 10 + a) * 128 + kq * 4);
                const int xi = (sg == 0) ? u : (128 + u * 3 + (sg - 1));
                #pragma unroll
                for (int n = 0; n < 8; ++n) {
                    const float xv = xs[nb + n][xi];
                    part[n][0] += xv * w.x;
                    part[n][1] += xv * w.y;
                    part[n][2] += xv * w.z;
                    part[n][3] += xv * w.w;
                }
            }
            #pragma unroll
            for (int n = 0; n < 8; ++n) {
                const float av = at[nb + n][a];
                acc[n][0] += av * part[n][0];
                acc[n][1] += av * part[n][1];
                acc[n][2] += av * part[n][2];
                acc[n][3] += av * part[n][3];
            }
        }
        #pragma unroll
        for (int n = 0; n < 8; ++n) {
            float* orow = out + (size_t)(n0 + nb + n) * 512;
            if (sg == 0) {
                *(float4*)(orow + kq * 4) =
                    make_float4(acc[n][0], acc[n][1], acc[n][2], acc[n][3]);
            } else {
                const int m = sg - 1;
                #pragma unroll
                for (int j = 0; j < 4; ++j)
                    orow[128 + (kq * 4 + j) * 3 + m] = acc[n][j];
            }
        }
    }
}

// ---------------------------------------------------------------------------
// CSR build: counts -> exclusive scan -> stable-ish scatter of edge ids.
// ---------------------------------------------------------------------------
__global__ __launch_bounds__(256) void hist_kernel(
    const int* __restrict__ recv, int* __restrict__ cnt)
{
    const int e = blockIdx.x * 256 + threadIdx.x;
    if (e < NE) atomicAdd(&cnt[recv[e]], 1);
}

__global__ __launch_bounds__(256) void scan_kernel(
    const int* __restrict__ cnt, int* __restrict__ row_start,
    int* __restrict__ head)
{
    __shared__ int part[256];
    const int t = threadIdx.x;
    const int base = t * 40;            // 250 threads x 40 bins = 10000
    int s = 0;
    if (base < NN)
        for (int b = 0; b < 40; ++b) s += cnt[base + b];
    part[t] = s;
    __syncthreads();
    const int local = s;
    for (int off = 1; off < 256; off <<= 1) {
        const int v = (t >= off) ? part[t - off] : 0;
        __syncthreads();
        part[t] += v;
        __syncthreads();
    }
    const int excl = part[t] - local;
    if (base < NN) {
        int run = excl;
        for (int b = 0; b < 40; ++b) {
            row_start[base + b] = run;
            head[base + b] = run;
            run += cnt[base + b];
        }
    }
    if (t == 0) row_start[NN] = NE;
}

__global__ __launch_bounds__(256) void scatter_kernel(
    const int* __restrict__ recv, int* __restrict__ head,
    int* __restrict__ elist)
{
    const int e = blockIdx.x * 256 + threadIdx.x;
    if (e < NE) {
        const int p = atomicAdd(&head[recv[e]], 1);
        elist[p] = e;
    }
}

// ---------------------------------------------------------------------------
// Kernel B': GATHER message accumulation — no fp32 atomics.
// Grid = 2500 node-groups x 2 half-blocks (quarters {0,1} / {2,3}).
// 256 threads: kk = t&127 (col within quarter), q = qbase + (t>>7).
// Per thread: W_tpw column (80 floats) in registers, static-indexed.
// tpw = sum_A at[A] * (sum_j ef[j] * W[A*8+j])   (90 FMA / edge)
// msgbuf[n][1024]: [0:128)=m0a, [128:256)=m0b, 256+m*256+k=m1a,
//                  256+m*256+128+k=m1b. Plain stores, full coverage.
// ---------------------------------------------------------------------------
__global__ __launch_bounds__(256) void gather_kernel(
    const float* __restrict__ node_attrs,
    const float* __restrict__ edge_attrs,
    const float* __restrict__ edge_feats,
    const int*  __restrict__ edge_index,
    const float* __restrict__ W_tpw,
    const float* __restrict__ hbuf,
    const int*  __restrict__ row_start,
    const int*  __restrict__ elist,
    float* __restrict__ msgbuf)
{
    __shared__ float eparam[32][24];
    // layout per edge: [0..7]=ef, [8..17]=at_sender, [18]=Y0, [19..21]=Y1,
    //                  [22]=bitcast(sender), [23]=pad
    const int t = threadIdx.x;
    const int kk = t & 127;
    const int qbase = (blockIdx.x & 1) * 2;
    const int q = qbase + (t >> 7);          // wave-uniform
    const int ngrp = blockIdx.x >> 1;
    const int c = q * 128 + kk;
    const int* __restrict__ sender = edge_index;

    float Wreg[80];
    #pragma unroll
    for (int a = 0; a < 80; ++a) Wreg[a] = W_tpw[a * 512 + c];

    for (int nn = 0; nn < 4; ++nn) {
        const int node = ngrp * 4 + nn;
        const int row = row_start[node];
        const int deg = row_start[node + 1] - row;
        float acc0 = 0.f, acc1 = 0.f, acc2 = 0.f;

        for (int ce = 0; ce < deg; ce += 32) {
            const int cl = min(32, deg - ce);
            __syncthreads();
            for (int idx = t; idx < cl * 24; idx += 256) {
                const int ii = idx / 24, f = idx - ii * 24;
                const int e = elist[row + ce + ii];
                float v;
                if (f < 8)       v = edge_feats[(size_t)e * 8 + f];
                else if (f < 18) v = node_attrs[(size_t)sender[e] * 10 + (f - 8)];
                else if (f < 22) v = edge_attrs[(size_t)e * 4 + (f - 18)];
                else if (f == 22) v = __int_as_float(sender[e]);
                else             v = 0.f;
                eparam[ii][f] = v;
            }
            __syncthreads();

            for (int i = 0; i < cl; ++i) {
                const float4* ep = (const float4*)(&eparam[i][0]);
                const float4 efA = ep[0], efB = ep[1];
                const float4 atA = ep[2], atB = ep[3];
                const float4 exC = ep[4], exD = ep[5];
                const int s = __float_as_int(exD.z);
                const float* hrow = hbuf + (size_t)s * 512;

                // issue sender-h loads early; latency hides under tpw FMAs
                float h0 = 0.f, h1a = 0.f, h1b = 0.f, h1c = 0.f;
                if (qbase == 0) {
                    h0 = hrow[kk];
                } else {
                    h1a = hrow[128 + kk];
                    h1b = hrow[256 + kk];
                    h1c = hrow[384 + kk];
                }

                const float efa[8]  = {efA.x, efA.y, efA.z, efA.w,
                                       efB.x, efB.y, efB.z, efB.w};
                const float ata[10] = {atA.x, atA.y, atA.z, atA.w,
                                       atB.x, atB.y, atB.z, atB.w,
                                       exC.x, exC.y};
                float tpw = 0.f;
                #pragma unroll
                for (int A = 0; A < 10; ++A) {
                    float sj = efa[0] * Wreg[A * 8];
                    #pragma unroll
                    for (int j = 1; j < 8; ++j)
                        sj = fmaf(efa[j], Wreg[A * 8 + j], sj);
                    tpw = fmaf(ata[A], sj, tpw);
                }

                const float Y0 = exC.z, Y10 = exC.w, Y11 = exD.x, Y12 = exD.y;
                if (q == 0) {
                    acc0 = fmaf(tpw * Y0, h0, acc0);
                } else if (q == 1) {
                    const float tm = tpw * h0;
                    acc0 = fmaf(tm, Y10, acc0);
                    acc1 = fmaf(tm, Y11, acc1);
                    acc2 = fmaf(tm, Y12, acc2);
                } else if (q == 2) {
                    const float t2 = tpw * Y0;
                    acc0 = fmaf(t2, h1a, acc0);
                    acc1 = fmaf(t2, h1b, acc1);
                    acc2 = fmaf(t2, h1c, acc2);
                } else {
                    float d = h1a * Y10;
                    d = fmaf(h1b, Y11, d);
                    d = fmaf(h1c, Y12, d);
                    acc0 = fmaf(tpw * INV_SQRT3F, d, acc0);
                }
            }
        }

        float* mrow = msgbuf + (size_t)node * 1024;
        if (q == 0) {
            mrow[kk] = acc0;
        } else if (q == 1) {
            mrow[256 + kk] = acc0;
            mrow[512 + kk] = acc1;
            mrow[768 + kk] = acc2;
        } else if (q == 2) {
            mrow[384 + kk] = acc0;
            mrow[640 + kk] = acc1;
            mrow[896 + kk] = acc2;
        } else {
            mrow[128 + kk] = acc0;
        }
    }
}

// ---------------------------------------------------------------------------
// Kernel C: out += (msg @ W_lin) / 16 (unchanged from R1).
// ---------------------------------------------------------------------------
__global__ __launch_bounds__(256) void out_kernel(
    const float* __restrict__ msgbuf,
    const float* __restrict__ W_lin0,
    const float* __restrict__ W_lin1,
    float* __restrict__ out)
{
    __shared__ float ms[16][256];
    const int t = threadIdx.x;
    const int n0 = blockIdx.x * 16;
    const int kq = t & 31;
    const int g  = t >> 5;

    for (int s = 0; s < 4; ++s) {
        __syncthreads();
        const int coff = (s == 0) ? 0 : (256 + (s - 1) * 256);
        for (int i = t; i < 1024; i += 256) {
            const int n = i >> 6, c4 = i & 63;
            ((float4*)&ms[n][0])[c4] =
                *(const float4*)(msgbuf + (size_t)(n0 + n) * 1024 + coff + c4 * 4);
        }
        __syncthreads();

        const float* __restrict__ Wl = (s == 0) ? W_lin0 : W_lin1;
        float acc[2][4];
        #pragma unroll
        for (int n = 0; n < 2; ++n)
            #pragma unroll
            for (int j = 0; j < 4; ++j) acc[n][j] = 0.f;

        for (int U = 0; U < 256; ++U) {
            const float4 w = *(const float4*)(Wl + U * 128 + kq * 4);
            #pragma unroll
            for (int n = 0; n < 2; ++n) {
                const float mv = ms[g * 2 + n][U];
                acc[n][0] += mv * w.x;
                acc[n][1] += mv * w.y;
                acc[n][2] += mv * w.z;
                acc[n][3] += mv * w.w;
            }
        }
        #pragma unroll
        for (int n = 0; n < 2; ++n) {
            float* orow = out + (size_t)(n0 + g * 2 + n) * 512;
            if (s == 0) {
                float4 o = *(float4*)(orow + kq * 4);
                o.x += acc[n][0] * INV_AVG;
                o.y += acc[n][1] * INV_AVG;
                o.z += acc[n][2] * INV_AVG;
                o.w += acc[n][3] * INV_AVG;
                *(float4*)(orow + kq * 4) = o;
            } else {
                const int m = s - 1;
                #pragma unroll
                for (int j = 0; j < 4; ++j)
                    orow[128 + (kq * 4 + j) * 3 + m] += acc[n][j] * INV_AVG;
            }
        }
    }
}

extern "C" void kernel_launch(void* const* d_in, const int* in_sizes, int n_in,
                              void* d_out, int out_size, void* d_ws, size_t ws_size,
                              hipStream_t stream) {
    const float* node_attrs = (const float*)d_in[0];
    const float* node_feats = (const float*)d_in[1];
    const float* edge_attrs = (const float*)d_in[2];
    const float* edge_feats = (const float*)d_in[3];
    const int*   edge_index = (const int*)d_in[4];
    const float* W_up0  = (const float*)d_in[5];
    const float* W_up1  = (const float*)d_in[6];
    const float* W_tpw  = (const float*)d_in[7];
    const float* W_lin0 = (const float*)d_in[8];
    const float* W_lin1 = (const float*)d_in[9];
    const float* W_sk0  = (const float*)d_in[10];
    const float* W_sk1  = (const float*)d_in[11];
    float* out = (float*)d_out;

    float* hbuf   = (float*)d_ws;                 // NN*512 f32
    float* msgbuf = hbuf + (size_t)NN * 512;      // NN*1024 f32
    int* cnt       = (int*)(msgbuf + (size_t)NN * 1024);
    int* row_start = cnt + NN;                    // NN+1
    int* head      = row_start + NN + 1;
    int* elist     = head + NN;                   // NE

    const int* recv = edge_index + NE;

    hipMemsetAsync(cnt, 0, NN * sizeof(int), stream);
    hist_kernel<<<(NE + 255) / 256, 256, 0, stream>>>(recv, cnt);
    scan_kernel<<<1, 256, 0, stream>>>(cnt, row_start, head);
    scatter_kernel<<<(NE + 255) / 256, 256, 0, stream>>>(recv, head, elist);

    node_kernel<<<NN / 16, 256, 0, stream>>>(node_attrs, node_feats,
                                             W_up0, W_up1, W_sk0, W_sk1,
                                             hbuf, out);
    gather_kernel<<<5000, 256, 0, stream>>>(node_attrs, edge_attrs, edge_feats,
                                            edge_index, W_tpw, hbuf,
                                            row_start, elist, msgbuf);
    out_kernel<<<NN / 16, 256, 0, stream>>>(msgbuf, W_lin0, W_lin1, out);
}

// Round 3
// 701.795 us; speedup vs baseline: 7.7527x; 1.8987x over previous
//
#include <hip/hip_runtime.h>

#define NN 10000
#define NE 160000
#define NB0 157            // ceil(10000/64) mode-0 blocks
#define NB1 469            // ceil(30000/64) mode-1 blocks

constexpr float INV_AVG = 1.0f / 16.0f;
constexpr float INV_SQRT3F = 0.5773502691896258f;

// ---------------------------------------------------------------------------
// Node stage as two fused GEMMs over "virtual rows".
//   mode0: row = node n          (10000 rows), weights W_up0 / W_sk0
//   mode1: row = n*3+m           (30000 rows), weights W_up1 / W_sk1
//   H : h[r][k]  = sum_u  x_r[u] * Wup[u][k]                  (K=128)
//   SC: sc[r][k] = sum_u sum_a (x_r[u]*at_r[a]) * Wsk[u][a][k] (K=1280)
// Block: 256 thr, 64 rows. Thread: kg=t&15 (8 k), rg=t>>4 (4 rows).
// acc[4][8]=32 regs, at in 40 regs; no `part` array (xa formed on the fly).
//   hbuf[n][512]: [0:128)=h0[k], 128+m*128+k = h1[n,k,m]
//   out [n][512]: [0:128)=sc0[n,k], 128+k*3+m = sc1[n,k,m]
// ---------------------------------------------------------------------------
__global__ __launch_bounds__(256, 3) void node_gemm_kernel(
    const float* __restrict__ node_attrs,
    const float* __restrict__ node_feats,
    const float* __restrict__ W_up0,
    const float* __restrict__ W_up1,
    const float* __restrict__ W_sk0,
    const float* __restrict__ W_sk1,
    float* __restrict__ hbuf,
    float* __restrict__ out)
{
    __shared__ float xrow[64][132];   // pad 132: rg stride 528B -> 2-way (free)
    __shared__ float atrow[64][10];

    const int t = threadIdx.x;
    const int bid = blockIdx.x;
    const bool m1 = (bid >= NB0);
    const int r0 = m1 ? (bid - NB0) * 64 : bid * 64;
    const int RTOT = m1 ? 30000 : 10000;

    // ---- stage x rows ----
    if (!m1) {
        for (int i = t; i < 64 * 32; i += 256) {      // float4 units
            const int r = i >> 5, c4 = i & 31;
            const int n = min(r0 + r, NN - 1);
            ((float4*)&xrow[r][0])[c4] =
                *(const float4*)(node_feats + (size_t)n * 512 + c4 * 4);
        }
    } else {
        for (int i = t; i < 64 * 128; i += 256) {
            const int r = i >> 7, u = i & 127;
            const int rr = min(r0 + r, 29999);
            const int n = rr / 3, m = rr - n * 3;
            xrow[r][u] = node_feats[(size_t)n * 512 + 128 + u * 3 + m];
        }
    }
    for (int i = t; i < 640; i += 256) {
        const int r = i / 10, a = i - r * 10;
        int n;
        if (!m1) n = min(r0 + r, NN - 1);
        else { const int rr = min(r0 + r, 29999); n = rr / 3; }
        atrow[r][a] = node_attrs[n * 10 + a];
    }
    __syncthreads();

    const int kg = t & 15;          // k = kg*8 .. +7
    const int rg = t >> 4;          // rows rg*4 .. +3
    const float* __restrict__ Wup = m1 ? W_up1 : W_up0;
    const float* __restrict__ Wsk = m1 ? W_sk1 : W_sk0;

    // ---- H phase: K=128 ----
    {
        float acc[4][8];
        #pragma unroll
        for (int r = 0; r < 4; ++r)
            #pragma unroll
            for (int j = 0; j < 8; ++j) acc[r][j] = 0.f;

        for (int u = 0; u < 128; ++u) {
            const float4 wa = *(const float4*)(Wup + u * 128 + kg * 8);
            const float4 wb = *(const float4*)(Wup + u * 128 + kg * 8 + 4);
            float xv[4];
            #pragma unroll
            for (int r = 0; r < 4; ++r) xv[r] = xrow[rg * 4 + r][u];
            #pragma unroll
            for (int r = 0; r < 4; ++r) {
                acc[r][0] = fmaf(xv[r], wa.x, acc[r][0]);
                acc[r][1] = fmaf(xv[r], wa.y, acc[r][1]);
                acc[r][2] = fmaf(xv[r], wa.z, acc[r][2]);
                acc[r][3] = fmaf(xv[r], wa.w, acc[r][3]);
                acc[r][4] = fmaf(xv[r], wb.x, acc[r][4]);
                acc[r][5] = fmaf(xv[r], wb.y, acc[r][5]);
                acc[r][6] = fmaf(xv[r], wb.z, acc[r][6]);
                acc[r][7] = fmaf(xv[r], wb.w, acc[r][7]);
            }
        }
        #pragma unroll
        for (int r = 0; r < 4; ++r) {
            const int rr = r0 + rg * 4 + r;
            if (rr >= RTOT) continue;
            float* dst;
            if (!m1) {
                dst = hbuf + (size_t)rr * 512 + kg * 8;
            } else {
                const int n = rr / 3, m = rr - n * 3;
                dst = hbuf + (size_t)n * 512 + 128 + m * 128 + kg * 8;
            }
            *(float4*)dst = make_float4(acc[r][0], acc[r][1], acc[r][2], acc[r][3]);
            *(float4*)(dst + 4) = make_float4(acc[r][4], acc[r][5], acc[r][6], acc[r][7]);
        }
    }

    // ---- at -> registers ----
    float atr[4][10];
    #pragma unroll
    for (int r = 0; r < 4; ++r)
        #pragma unroll
        for (int a = 0; a < 10; ++a) atr[r][a] = atrow[rg * 4 + r][a];

    // ---- SC phase: K=1280 (u-major, a inner; W_sk native layout u,a,k) ----
    {
        float acc[4][8];
        #pragma unroll
        for (int r = 0; r < 4; ++r)
            #pragma unroll
            for (int j = 0; j < 8; ++j) acc[r][j] = 0.f;

        for (int u = 0; u < 128; ++u) {
            float xv[4];
            #pragma unroll
            for (int r = 0; r < 4; ++r) xv[r] = xrow[rg * 4 + r][u];
            const float* wbase = Wsk + (size_t)u * 1280 + kg * 8;
            #pragma unroll
            for (int a = 0; a < 10; ++a) {
                const float4 wa = *(const float4*)(wbase + a * 128);
                const float4 wb = *(const float4*)(wbase + a * 128 + 4);
                float xa[4];
                #pragma unroll
                for (int r = 0; r < 4; ++r) xa[r] = xv[r] * atr[r][a];
                #pragma unroll
                for (int r = 0; r < 4; ++r) {
                    acc[r][0] = fmaf(xa[r], wa.x, acc[r][0]);
                    acc[r][1] = fmaf(xa[r], wa.y, acc[r][1]);
                    acc[r][2] = fmaf(xa[r], wa.z, acc[r][2]);
                    acc[r][3] = fmaf(xa[r], wa.w, acc[r][3]);
                    acc[r][4] = fmaf(xa[r], wb.x, acc[r][4]);
                    acc[r][5] = fmaf(xa[r], wb.y, acc[r][5]);
                    acc[r][6] = fmaf(xa[r], wb.z, acc[r][6]);
                    acc[r][7] = fmaf(xa[r], wb.w, acc[r][7]);
                }
            }
        }
        #pragma unroll
        for (int r = 0; r < 4; ++r) {
            const int rr = r0 + rg * 4 + r;
            if (rr >= RTOT) continue;
            if (!m1) {
                float* dst = out + (size_t)rr * 512 + kg * 8;
                *(float4*)dst = make_float4(acc[r][0], acc[r][1], acc[r][2], acc[r][3]);
                *(float4*)(dst + 4) = make_float4(acc[r][4], acc[r][5], acc[r][6], acc[r][7]);
            } else {
                const int n = rr / 3, m = rr - n * 3;
                float* orow = out + (size_t)n * 512 + 128 + m;
                #pragma unroll
                for (int j = 0; j < 8; ++j)
                    orow[(kg * 8 + j) * 3] = acc[r][j];
            }
        }
    }
}

// ---------------------------------------------------------------------------
// CSR build (unchanged).
// ---------------------------------------------------------------------------
__global__ __launch_bounds__(256) void hist_kernel(
    const int* __restrict__ recv, int* __restrict__ cnt)
{
    const int e = blockIdx.x * 256 + threadIdx.x;
    if (e < NE) atomicAdd(&cnt[recv[e]], 1);
}

__global__ __launch_bounds__(256) void scan_kernel(
    const int* __restrict__ cnt, int* __restrict__ row_start,
    int* __restrict__ head)
{
    __shared__ int part[256];
    const int t = threadIdx.x;
    const int base = t * 40;
    int s = 0;
    if (base < NN)
        for (int b = 0; b < 40; ++b) s += cnt[base + b];
    part[t] = s;
    __syncthreads();
    const int local = s;
    for (int off = 1; off < 256; off <<= 1) {
        const int v = (t >= off) ? part[t - off] : 0;
        __syncthreads();
        part[t] += v;
        __syncthreads();
    }
    const int excl = part[t] - local;
    if (base < NN) {
        int run = excl;
        for (int b = 0; b < 40; ++b) {
            row_start[base + b] = run;
            head[base + b] = run;
            run += cnt[base + b];
        }
    }
    if (t == 0) row_start[NN] = NE;
}

__global__ __launch_bounds__(256) void scatter_kernel(
    const int* __restrict__ recv, int* __restrict__ head,
    int* __restrict__ elist)
{
    const int e = blockIdx.x * 256 + threadIdx.x;
    if (e < NE) {
        const int p = atomicAdd(&head[recv[e]], 1);
        elist[p] = e;
    }
}

// ---------------------------------------------------------------------------
// Gather message accumulation (unchanged from R2).
// ---------------------------------------------------------------------------
__global__ __launch_bounds__(256) void gather_kernel(
    const float* __restrict__ node_attrs,
    const float* __restrict__ edge_attrs,
    const float* __restrict__ edge_feats,
    const int*  __restrict__ edge_index,
    const float* __restrict__ W_tpw,
    const float* __restrict__ hbuf,
    const int*  __restrict__ row_start,
    const int*  __restrict__ elist,
    float* __restrict__ msgbuf)
{
    __shared__ float eparam[32][24];
    const int t = threadIdx.x;
    const int kk = t & 127;
    const int qbase = (blockIdx.x & 1) * 2;
    const int q = qbase + (t >> 7);
    const int ngrp = blockIdx.x >> 1;
    const int c = q * 128 + kk;
    const int* __restrict__ sender = edge_index;

    float Wreg[80];
    #pragma unroll
    for (int a = 0; a < 80; ++a) Wreg[a] = W_tpw[a * 512 + c];

    for (int nn = 0; nn < 4; ++nn) {
        const int node = ngrp * 4 + nn;
        const int row = row_start[node];
        const int deg = row_start[node + 1] - row;
        float acc0 = 0.f, acc1 = 0.f, acc2 = 0.f;

        for (int ce = 0; ce < deg; ce += 32) {
            const int cl = min(32, deg - ce);
            __syncthreads();
            for (int idx = t; idx < cl * 24; idx += 256) {
                const int ii = idx / 24, f = idx - ii * 24;
                const int e = elist[row + ce + ii];
                float v;
                if (f < 8)       v = edge_feats[(size_t)e * 8 + f];
                else if (f < 18) v = node_attrs[(size_t)sender[e] * 10 + (f - 8)];
                else if (f < 22) v = edge_attrs[(size_t)e * 4 + (f - 18)];
                else if (f == 22) v = __int_as_float(sender[e]);
                else             v = 0.f;
                eparam[ii][f] = v;
            }
            __syncthreads();

            for (int i = 0; i < cl; ++i) {
                const float4* ep = (const float4*)(&eparam[i][0]);
                const float4 efA = ep[0], efB = ep[1];
                const float4 atA = ep[2], atB = ep[3];
                const float4 exC = ep[4], exD = ep[5];
                const int s = __float_as_int(exD.z);
                const float* hrow = hbuf + (size_t)s * 512;

                float h0 = 0.f, h1a = 0.f, h1b = 0.f, h1c = 0.f;
                if (qbase == 0) {
                    h0 = hrow[kk];
                } else {
                    h1a = hrow[128 + kk];
                    h1b = hrow[256 + kk];
                    h1c = hrow[384 + kk];
                }

                const float efa[8]  = {efA.x, efA.y, efA.z, efA.w,
                                       efB.x, efB.y, efB.z, efB.w};
                const float ata[10] = {atA.x, atA.y, atA.z, atA.w,
                                       atB.x, atB.y, atB.z, atB.w,
                                       exC.x, exC.y};
                float tpw = 0.f;
                #pragma unroll
                for (int A = 0; A < 10; ++A) {
                    float sj = efa[0] * Wreg[A * 8];
                    #pragma unroll
                    for (int j = 1; j < 8; ++j)
                        sj = fmaf(efa[j], Wreg[A * 8 + j], sj);
                    tpw = fmaf(ata[A], sj, tpw);
                }

                const float Y0 = exC.z, Y10 = exC.w, Y11 = exD.x, Y12 = exD.y;
                if (q == 0) {
                    acc0 = fmaf(tpw * Y0, h0, acc0);
                } else if (q == 1) {
                    const float tm = tpw * h0;
                    acc0 = fmaf(tm, Y10, acc0);
                    acc1 = fmaf(tm, Y11, acc1);
                    acc2 = fmaf(tm, Y12, acc2);
                } else if (q == 2) {
                    const float t2 = tpw * Y0;
                    acc0 = fmaf(t2, h1a, acc0);
                    acc1 = fmaf(t2, h1b, acc1);
                    acc2 = fmaf(t2, h1c, acc2);
                } else {
                    float d = h1a * Y10;
                    d = fmaf(h1b, Y11, d);
                    d = fmaf(h1c, Y12, d);
                    acc0 = fmaf(tpw * INV_SQRT3F, d, acc0);
                }
            }
        }

        float* mrow = msgbuf + (size_t)node * 1024;
        if (q == 0) {
            mrow[kk] = acc0;
        } else if (q == 1) {
            mrow[256 + kk] = acc0;
            mrow[512 + kk] = acc1;
            mrow[768 + kk] = acc2;
        } else if (q == 2) {
            mrow[384 + kk] = acc0;
            mrow[640 + kk] = acc1;
            mrow[896 + kk] = acc2;
        } else {
            mrow[128 + kk] = acc0;
        }
    }
}

// ---------------------------------------------------------------------------
// out += (msg @ W_lin) / 16 (unchanged).
// ---------------------------------------------------------------------------
__global__ __launch_bounds__(256) void out_kernel(
    const float* __restrict__ msgbuf,
    const float* __restrict__ W_lin0,
    const float* __restrict__ W_lin1,
    float* __restrict__ out)
{
    __shared__ float ms[16][256];
    const int t = threadIdx.x;
    const int n0 = blockIdx.x * 16;
    const int kq = t & 31;
    const int g  = t >> 5;

    for (int s = 0; s < 4; ++s) {
        __syncthreads();
        const int coff = (s == 0) ? 0 : (256 + (s - 1) * 256);
        for (int i = t; i < 1024; i += 256) {
            const int n = i >> 6, c4 = i & 63;
            ((float4*)&ms[n][0])[c4] =
                *(const float4*)(msgbuf + (size_t)(n0 + n) * 1024 + coff + c4 * 4);
        }
        __syncthreads();

        const float* __restrict__ Wl = (s == 0) ? W_lin0 : W_lin1;
        float acc[2][4];
        #pragma unroll
        for (int n = 0; n < 2; ++n)
            #pragma unroll
            for (int j = 0; j < 4; ++j) acc[n][j] = 0.f;

        for (int U = 0; U < 256; ++U) {
            const float4 w = *(const float4*)(Wl + U * 128 + kq * 4);
            #pragma unroll
            for (int n = 0; n < 2; ++n) {
                const float mv = ms[g * 2 + n][U];
                acc[n][0] += mv * w.x;
                acc[n][1] += mv * w.y;
                acc[n][2] += mv * w.z;
                acc[n][3] += mv * w.w;
            }
        }
        #pragma unroll
        for (int n = 0; n < 2; ++n) {
            float* orow = out + (size_t)(n0 + g * 2 + n) * 512;
            if (s == 0) {
                float4 o = *(float4*)(orow + kq * 4);
                o.x += acc[n][0] * INV_AVG;
                o.y += acc[n][1] * INV_AVG;
                o.z += acc[n][2] * INV_AVG;
                o.w += acc[n][3] * INV_AVG;
                *(float4*)(orow + kq * 4) = o;
            } else {
                const int m = s - 1;
                #pragma unroll
                for (int j = 0; j < 4; ++j)
                    orow[128 + (kq * 4 + j) * 3 + m] += acc[n][j] * INV_AVG;
            }
        }
    }
}

extern "C" void kernel_launch(void* const* d_in, const int* in_sizes, int n_in,
                              void* d_out, int out_size, void* d_ws, size_t ws_size,
                              hipStream_t stream) {
    const float* node_attrs = (const float*)d_in[0];
    const float* node_feats = (const float*)d_in[1];
    const float* edge_attrs = (const float*)d_in[2];
    const float* edge_feats = (const float*)d_in[3];
    const int*   edge_index = (const int*)d_in[4];
    const float* W_up0  = (const float*)d_in[5];
    const float* W_up1  = (const float*)d_in[6];
    const float* W_tpw  = (const float*)d_in[7];
    const float* W_lin0 = (const float*)d_in[8];
    const float* W_lin1 = (const float*)d_in[9];
    const float* W_sk0  = (const float*)d_in[10];
    const float* W_sk1  = (const float*)d_in[11];
    float* out = (float*)d_out;

    float* hbuf   = (float*)d_ws;                 // NN*512 f32
    float* msgbuf = hbuf + (size_t)NN * 512;      // NN*1024 f32
    int* cnt       = (int*)(msgbuf + (size_t)NN * 1024);
    int* row_start = cnt + NN;                    // NN+1
    int* head      = row_start + NN + 1;
    int* elist     = head + NN;                   // NE

    const int* recv = edge_index + NE;

    hipMemsetAsync(cnt, 0, NN * sizeof(int), stream);
    hist_kernel<<<(NE + 255) / 256, 256, 0, stream>>>(recv, cnt);
    scan_kernel<<<1, 256, 0, stream>>>(cnt, row_start, head);
    scatter_kernel<<<(NE + 255) / 256, 256, 0, stream>>>(recv, head, elist);

    node_gemm_kernel<<<NB0 + NB1, 256, 0, stream>>>(node_attrs, node_feats,
                                                    W_up0, W_up1, W_sk0, W_sk1,
                                                    hbuf, out);
    gather_kernel<<<5000, 256, 0, stream>>>(node_attrs, edge_attrs, edge_feats,
                                            edge_index, W_tpw, hbuf,
                                            row_start, elist, msgbuf);
    out_kernel<<<NN / 16, 256, 0, stream>>>(msgbuf, W_lin0, W_lin1, out);
}

// Round 4
// 663.608 us; speedup vs baseline: 8.1988x; 1.0575x over previous
//
#include <hip/hip_runtime.h>

#define NN 10000
#define NE 160000
#define NB0 157            // ceil(10000/64) mode-0 blocks
#define NB1 469            // ceil(30000/64) mode-1 blocks

constexpr float INV_AVG = 1.0f / 16.0f;
constexpr float INV_SQRT3F = 0.5773502691896258f;

// ---------------------------------------------------------------------------
// Node stage as two fused GEMMs over "virtual rows" (unchanged from R3).
// ---------------------------------------------------------------------------
__global__ __launch_bounds__(256, 3) void node_gemm_kernel(
    const float* __restrict__ node_attrs,
    const float* __restrict__ node_feats,
    const float* __restrict__ W_up0,
    const float* __restrict__ W_up1,
    const float* __restrict__ W_sk0,
    const float* __restrict__ W_sk1,
    float* __restrict__ hbuf,
    float* __restrict__ out)
{
    __shared__ float xrow[64][132];
    __shared__ float atrow[64][10];

    const int t = threadIdx.x;
    const int bid = blockIdx.x;
    const bool m1 = (bid >= NB0);
    const int r0 = m1 ? (bid - NB0) * 64 : bid * 64;
    const int RTOT = m1 ? 30000 : 10000;

    if (!m1) {
        for (int i = t; i < 64 * 32; i += 256) {
            const int r = i >> 5, c4 = i & 31;
            const int n = min(r0 + r, NN - 1);
            ((float4*)&xrow[r][0])[c4] =
                *(const float4*)(node_feats + (size_t)n * 512 + c4 * 4);
        }
    } else {
        for (int i = t; i < 64 * 128; i += 256) {
            const int r = i >> 7, u = i & 127;
            const int rr = min(r0 + r, 29999);
            const int n = rr / 3, m = rr - n * 3;
            xrow[r][u] = node_feats[(size_t)n * 512 + 128 + u * 3 + m];
        }
    }
    for (int i = t; i < 640; i += 256) {
        const int r = i / 10, a = i - r * 10;
        int n;
        if (!m1) n = min(r0 + r, NN - 1);
        else { const int rr = min(r0 + r, 29999); n = rr / 3; }
        atrow[r][a] = node_attrs[n * 10 + a];
    }
    __syncthreads();

    const int kg = t & 15;
    const int rg = t >> 4;
    const float* __restrict__ Wup = m1 ? W_up1 : W_up0;
    const float* __restrict__ Wsk = m1 ? W_sk1 : W_sk0;

    // ---- H phase ----
    {
        float acc[4][8];
        #pragma unroll
        for (int r = 0; r < 4; ++r)
            #pragma unroll
            for (int j = 0; j < 8; ++j) acc[r][j] = 0.f;

        for (int u = 0; u < 128; ++u) {
            const float4 wa = *(const float4*)(Wup + u * 128 + kg * 8);
            const float4 wb = *(const float4*)(Wup + u * 128 + kg * 8 + 4);
            float xv[4];
            #pragma unroll
            for (int r = 0; r < 4; ++r) xv[r] = xrow[rg * 4 + r][u];
            #pragma unroll
            for (int r = 0; r < 4; ++r) {
                acc[r][0] = fmaf(xv[r], wa.x, acc[r][0]);
                acc[r][1] = fmaf(xv[r], wa.y, acc[r][1]);
                acc[r][2] = fmaf(xv[r], wa.z, acc[r][2]);
                acc[r][3] = fmaf(xv[r], wa.w, acc[r][3]);
                acc[r][4] = fmaf(xv[r], wb.x, acc[r][4]);
                acc[r][5] = fmaf(xv[r], wb.y, acc[r][5]);
                acc[r][6] = fmaf(xv[r], wb.z, acc[r][6]);
                acc[r][7] = fmaf(xv[r], wb.w, acc[r][7]);
            }
        }
        #pragma unroll
        for (int r = 0; r < 4; ++r) {
            const int rr = r0 + rg * 4 + r;
            if (rr >= RTOT) continue;
            float* dst;
            if (!m1) {
                dst = hbuf + (size_t)rr * 512 + kg * 8;
            } else {
                const int n = rr / 3, m = rr - n * 3;
                dst = hbuf + (size_t)n * 512 + 128 + m * 128 + kg * 8;
            }
            *(float4*)dst = make_float4(acc[r][0], acc[r][1], acc[r][2], acc[r][3]);
            *(float4*)(dst + 4) = make_float4(acc[r][4], acc[r][5], acc[r][6], acc[r][7]);
        }
    }

    float atr[4][10];
    #pragma unroll
    for (int r = 0; r < 4; ++r)
        #pragma unroll
        for (int a = 0; a < 10; ++a) atr[r][a] = atrow[rg * 4 + r][a];

    // ---- SC phase ----
    {
        float acc[4][8];
        #pragma unroll
        for (int r = 0; r < 4; ++r)
            #pragma unroll
            for (int j = 0; j < 8; ++j) acc[r][j] = 0.f;

        for (int u = 0; u < 128; ++u) {
            float xv[4];
            #pragma unroll
            for (int r = 0; r < 4; ++r) xv[r] = xrow[rg * 4 + r][u];
            const float* wbase = Wsk + (size_t)u * 1280 + kg * 8;
            #pragma unroll
            for (int a = 0; a < 10; ++a) {
                const float4 wa = *(const float4*)(wbase + a * 128);
                const float4 wb = *(const float4*)(wbase + a * 128 + 4);
                float xa[4];
                #pragma unroll
                for (int r = 0; r < 4; ++r) xa[r] = xv[r] * atr[r][a];
                #pragma unroll
                for (int r = 0; r < 4; ++r) {
                    acc[r][0] = fmaf(xa[r], wa.x, acc[r][0]);
                    acc[r][1] = fmaf(xa[r], wa.y, acc[r][1]);
                    acc[r][2] = fmaf(xa[r], wa.z, acc[r][2]);
                    acc[r][3] = fmaf(xa[r], wa.w, acc[r][3]);
                    acc[r][4] = fmaf(xa[r], wb.x, acc[r][4]);
                    acc[r][5] = fmaf(xa[r], wb.y, acc[r][5]);
                    acc[r][6] = fmaf(xa[r], wb.z, acc[r][6]);
                    acc[r][7] = fmaf(xa[r], wb.w, acc[r][7]);
                }
            }
        }
        #pragma unroll
        for (int r = 0; r < 4; ++r) {
            const int rr = r0 + rg * 4 + r;
            if (rr >= RTOT) continue;
            if (!m1) {
                float* dst = out + (size_t)rr * 512 + kg * 8;
                *(float4*)dst = make_float4(acc[r][0], acc[r][1], acc[r][2], acc[r][3]);
                *(float4*)(dst + 4) = make_float4(acc[r][4], acc[r][5], acc[r][6], acc[r][7]);
            } else {
                const int n = rr / 3, m = rr - n * 3;
                float* orow = out + (size_t)n * 512 + 128 + m;
                #pragma unroll
                for (int j = 0; j < 8; ++j)
                    orow[(kg * 8 + j) * 3] = acc[r][j];
            }
        }
    }
}

// ---------------------------------------------------------------------------
// CSR build (unchanged).
// ---------------------------------------------------------------------------
__global__ __launch_bounds__(256) void hist_kernel(
    const int* __restrict__ recv, int* __restrict__ cnt)
{
    const int e = blockIdx.x * 256 + threadIdx.x;
    if (e < NE) atomicAdd(&cnt[recv[e]], 1);
}

__global__ __launch_bounds__(256) void scan_kernel(
    const int* __restrict__ cnt, int* __restrict__ row_start,
    int* __restrict__ head)
{
    __shared__ int part[256];
    const int t = threadIdx.x;
    const int base = t * 40;
    int s = 0;
    if (base < NN)
        for (int b = 0; b < 40; ++b) s += cnt[base + b];
    part[t] = s;
    __syncthreads();
    const int local = s;
    for (int off = 1; off < 256; off <<= 1) {
        const int v = (t >= off) ? part[t - off] : 0;
        __syncthreads();
        part[t] += v;
        __syncthreads();
    }
    const int excl = part[t] - local;
    if (base < NN) {
        int run = excl;
        for (int b = 0; b < 40; ++b) {
            row_start[base + b] = run;
            head[base + b] = run;
            run += cnt[base + b];
        }
    }
    if (t == 0) row_start[NN] = NE;
}

__global__ __launch_bounds__(256) void scatter_kernel(
    const int* __restrict__ recv, int* __restrict__ head,
    int* __restrict__ elist)
{
    const int e = blockIdx.x * 256 + threadIdx.x;
    if (e < NE) {
        const int p = atomicAdd(&head[recv[e]], 1);
        elist[p] = e;
    }
}

// ---------------------------------------------------------------------------
// Pack kernel: materialize per-edge params in CSR (elist) order, once.
// pk[p][24]: [0..7]=ef, [8..17]=at_sender, [18]=Y0, [19..21]=Y1,
//            [22]=bitcast(sender), [23]=pad.  NE/64 = 2500 blocks.
// ---------------------------------------------------------------------------
__global__ __launch_bounds__(256) void pack_kernel(
    const float* __restrict__ node_attrs,
    const float* __restrict__ edge_attrs,
    const float* __restrict__ edge_feats,
    const int*  __restrict__ edge_index,
    const int*  __restrict__ elist,
    float* __restrict__ pk)
{
    __shared__ float buf[64][24];
    __shared__ int es[64];
    const int t = threadIdx.x;
    const int p0 = blockIdx.x * 64;

    if (t < 64) es[t] = elist[p0 + t];
    __syncthreads();

    for (int idx = t; idx < 64 * 24; idx += 256) {
        const int ii = idx / 24, f = idx - ii * 24;
        const int e = es[ii];
        float v;
        if (f < 8)        v = edge_feats[(size_t)e * 8 + f];
        else if (f < 18)  v = node_attrs[(size_t)edge_index[e] * 10 + (f - 8)];
        else if (f < 22)  v = edge_attrs[(size_t)e * 4 + (f - 18)];
        else if (f == 22) v = __int_as_float(edge_index[e]);
        else              v = 0.f;
        buf[ii][f] = v;
    }
    __syncthreads();

    float4* dst = (float4*)(pk + (size_t)p0 * 24);
    const float4* srcb = (const float4*)&buf[0][0];
    for (int idx = t; idx < 64 * 6; idx += 256)
        dst[idx] = srcb[idx];
}

// ---------------------------------------------------------------------------
// Gather v2: W column truly register-resident (launch_bounds(256,2) -> 128
// VGPR budget), staging = coalesced float4 copy from packed params.
// ---------------------------------------------------------------------------
__global__ __launch_bounds__(256, 2) void gather_kernel(
    const float* __restrict__ W_tpw,
    const float* __restrict__ hbuf,
    const int*  __restrict__ row_start,
    const float* __restrict__ pk,
    float* __restrict__ msgbuf)
{
    __shared__ float eparam[32][24];
    const int t = threadIdx.x;
    const int kk = t & 127;
    const int qbase = (blockIdx.x & 1) * 2;
    const int q = qbase + (t >> 7);          // wave-uniform
    const int ngrp = blockIdx.x >> 1;
    const int c = q * 128 + kk;

    float Wreg[80];
    #pragma unroll
    for (int a = 0; a < 80; ++a) Wreg[a] = W_tpw[a * 512 + c];

    for (int nn = 0; nn < 4; ++nn) {
        const int node = ngrp * 4 + nn;
        const int row = row_start[node];
        const int deg = row_start[node + 1] - row;
        float acc0 = 0.f, acc1 = 0.f, acc2 = 0.f;

        for (int ce = 0; ce < deg; ce += 32) {
            const int cl = min(32, deg - ce);
            __syncthreads();
            {
                const float4* src = (const float4*)(pk + (size_t)(row + ce) * 24);
                if (t < cl * 6) ((float4*)&eparam[0][0])[t] = src[t];
            }
            __syncthreads();

            for (int i = 0; i < cl; ++i) {
                const float4* ep = (const float4*)(&eparam[i][0]);
                const float4 efA = ep[0], efB = ep[1];
                const float4 atA = ep[2], atB = ep[3];
                const float4 exC = ep[4], exD = ep[5];
                const int s = __float_as_int(exD.z);
                const float* hrow = hbuf + (size_t)s * 512;

                float h0 = 0.f, h1a = 0.f, h1b = 0.f, h1c = 0.f;
                if (qbase == 0) {
                    h0 = hrow[kk];
                } else {
                    h1a = hrow[128 + kk];
                    h1b = hrow[256 + kk];
                    h1c = hrow[384 + kk];
                }

                const float efa[8]  = {efA.x, efA.y, efA.z, efA.w,
                                       efB.x, efB.y, efB.z, efB.w};
                const float ata[10] = {atA.x, atA.y, atA.z, atA.w,
                                       atB.x, atB.y, atB.z, atB.w,
                                       exC.x, exC.y};
                float tpw = 0.f;
                #pragma unroll
                for (int A = 0; A < 10; ++A) {
                    float sj = efa[0] * Wreg[A * 8];
                    #pragma unroll
                    for (int j = 1; j < 8; ++j)
                        sj = fmaf(efa[j], Wreg[A * 8 + j], sj);
                    tpw = fmaf(ata[A], sj, tpw);
                }

                const float Y0 = exC.z, Y10 = exC.w, Y11 = exD.x, Y12 = exD.y;
                if (q == 0) {
                    acc0 = fmaf(tpw * Y0, h0, acc0);
                } else if (q == 1) {
                    const float tm = tpw * h0;
                    acc0 = fmaf(tm, Y10, acc0);
                    acc1 = fmaf(tm, Y11, acc1);
                    acc2 = fmaf(tm, Y12, acc2);
                } else if (q == 2) {
                    const float t2 = tpw * Y0;
                    acc0 = fmaf(t2, h1a, acc0);
                    acc1 = fmaf(t2, h1b, acc1);
                    acc2 = fmaf(t2, h1c, acc2);
                } else {
                    float d = h1a * Y10;
                    d = fmaf(h1b, Y11, d);
                    d = fmaf(h1c, Y12, d);
                    acc0 = fmaf(tpw * INV_SQRT3F, d, acc0);
                }
            }
        }

        float* mrow = msgbuf + (size_t)node * 1024;
        if (q == 0) {
            mrow[kk] = acc0;
        } else if (q == 1) {
            mrow[256 + kk] = acc0;
            mrow[512 + kk] = acc1;
            mrow[768 + kk] = acc2;
        } else if (q == 2) {
            mrow[384 + kk] = acc0;
            mrow[640 + kk] = acc1;
            mrow[896 + kk] = acc2;
        } else {
            mrow[128 + kk] = acc0;
        }
    }
}

// ---------------------------------------------------------------------------
// out += (msg @ W_lin) / 16 (unchanged).
// ---------------------------------------------------------------------------
__global__ __launch_bounds__(256) void out_kernel(
    const float* __restrict__ msgbuf,
    const float* __restrict__ W_lin0,
    const float* __restrict__ W_lin1,
    float* __restrict__ out)
{
    __shared__ float ms[16][256];
    const int t = threadIdx.x;
    const int n0 = blockIdx.x * 16;
    const int kq = t & 31;
    const int g  = t >> 5;

    for (int s = 0; s < 4; ++s) {
        __syncthreads();
        const int coff = (s == 0) ? 0 : (256 + (s - 1) * 256);
        for (int i = t; i < 1024; i += 256) {
            const int n = i >> 6, c4 = i & 63;
            ((float4*)&ms[n][0])[c4] =
                *(const float4*)(msgbuf + (size_t)(n0 + n) * 1024 + coff + c4 * 4);
        }
        __syncthreads();

        const float* __restrict__ Wl = (s == 0) ? W_lin0 : W_lin1;
        float acc[2][4];
        #pragma unroll
        for (int n = 0; n < 2; ++n)
            #pragma unroll
            for (int j = 0; j < 4; ++j) acc[n][j] = 0.f;

        for (int U = 0; U < 256; ++U) {
            const float4 w = *(const float4*)(Wl + U * 128 + kq * 4);
            #pragma unroll
            for (int n = 0; n < 2; ++n) {
                const float mv = ms[g * 2 + n][U];
                acc[n][0] += mv * w.x;
                acc[n][1] += mv * w.y;
                acc[n][2] += mv * w.z;
                acc[n][3] += mv * w.w;
            }
        }
        #pragma unroll
        for (int n = 0; n < 2; ++n) {
            float* orow = out + (size_t)(n0 + g * 2 + n) * 512;
            if (s == 0) {
                float4 o = *(float4*)(orow + kq * 4);
                o.x += acc[n][0] * INV_AVG;
                o.y += acc[n][1] * INV_AVG;
                o.z += acc[n][2] * INV_AVG;
                o.w += acc[n][3] * INV_AVG;
                *(float4*)(orow + kq * 4) = o;
            } else {
                const int m = s - 1;
                #pragma unroll
                for (int j = 0; j < 4; ++j)
                    orow[128 + (kq * 4 + j) * 3 + m] += acc[n][j] * INV_AVG;
            }
        }
    }
}

extern "C" void kernel_launch(void* const* d_in, const int* in_sizes, int n_in,
                              void* d_out, int out_size, void* d_ws, size_t ws_size,
                              hipStream_t stream) {
    const float* node_attrs = (const float*)d_in[0];
    const float* node_feats = (const float*)d_in[1];
    const float* edge_attrs = (const float*)d_in[2];
    const float* edge_feats = (const float*)d_in[3];
    const int*   edge_index = (const int*)d_in[4];
    const float* W_up0  = (const float*)d_in[5];
    const float* W_up1  = (const float*)d_in[6];
    const float* W_tpw  = (const float*)d_in[7];
    const float* W_lin0 = (const float*)d_in[8];
    const float* W_lin1 = (const float*)d_in[9];
    const float* W_sk0  = (const float*)d_in[10];
    const float* W_sk1  = (const float*)d_in[11];
    float* out = (float*)d_out;

    float* hbuf   = (float*)d_ws;                     // NN*512 f32
    float* msgbuf = hbuf + (size_t)NN * 512;          // NN*1024 f32
    float* pk     = msgbuf + (size_t)NN * 1024;       // NE*24 f32
    int* cnt       = (int*)(pk + (size_t)NE * 24);
    int* row_start = cnt + NN;                        // NN+1
    int* head      = row_start + NN + 1;
    int* elist     = head + NN;                       // NE

    const int* recv = edge_index + NE;

    hipMemsetAsync(cnt, 0, NN * sizeof(int), stream);
    hist_kernel<<<(NE + 255) / 256, 256, 0, stream>>>(recv, cnt);
    scan_kernel<<<1, 256, 0, stream>>>(cnt, row_start, head);
    scatter_kernel<<<(NE + 255) / 256, 256, 0, stream>>>(recv, head, elist);
    pack_kernel<<<NE / 64, 256, 0, stream>>>(node_attrs, edge_attrs, edge_feats,
                                             edge_index, elist, pk);

    node_gemm_kernel<<<NB0 + NB1, 256, 0, stream>>>(node_attrs, node_feats,
                                                    W_up0, W_up1, W_sk0, W_sk1,
                                                    hbuf, out);
    gather_kernel<<<5000, 256, 0, stream>>>(W_tpw, hbuf, row_start, pk, msgbuf);
    out_kernel<<<NN / 16, 256, 0, stream>>>(msgbuf, W_lin0, W_lin1, out);
}